// Round 3
// baseline (145.680 us; speedup 1.0000x reference)
//
#include <hip/hip_runtime.h>
#include <hip/hip_fp16.h>

// B=8, T=S=512, M=N=512, H=128
// score[b,t,s] = (1/sqrt(512)) * sum_h v[h]*tanh(x1[b,t,h]+x2[b,s,h])
// tanh(x) = 1 - 2/(1+e^{2x}) => score = (Sv - 2*sum_h v_h/(1+e_h))/SCALE,
//   e = exp2(z1+z2), z = 2*log2e*x.  proj packs exp2(z) = em*2^k as
//   (int16 k | fp16 em).  Hot loop: e = ldexp(emt*ems, min(kt+ks,30)),
//   4-way-over-h rcp merge, float2(v_pk_f32)-packed over s-pairs.

typedef float vf2 __attribute__((ext_vector_type(2)));

constexpr float SCALE_IN  = 2.8853900817779268f;   // 2*log2(e)
constexpr float INV_SCALE = 0.04419417382415922f;  // 1/sqrt(512)

// ---------------- Projection GEMM + exp-factor pack --------------------------
// Grid 512 (256 per matrix), 256 threads. Block: 16 rows x 128 h.
// LDS: A 16x64 (4KB) + W 64x128 (32KB). Thread tile: 2 rows x 4 h.
__global__ __launch_bounds__(256) void proj_kernel(
    const float* __restrict__ q,  const float* __restrict__ w2,
    const float* __restrict__ ky, const float* __restrict__ w1,
    unsigned int* __restrict__ x1w, unsigned int* __restrict__ x2w) {
  __shared__ float As[16 * 64];
  __shared__ float Ws[64 * 128];

  int blk = blockIdx.x;
  const float* A; const float* W; unsigned int* O;
  if (blk < 256) { A = q;  W = w2; O = x1w; }
  else           { blk -= 256; A = ky; W = w1; O = x2w; }
  const int rbase = blk * 16;
  const int tid = threadIdx.x;
  const int hq  = tid & 31;        // h = 4*hq + {0..3}
  const int rg  = tid >> 5;        // rows 2*rg, 2*rg+1

  float acc[2][4];
#pragma unroll
  for (int r = 0; r < 2; ++r)
#pragma unroll
    for (int c = 0; c < 4; ++c) acc[r][c] = 0.0f;

  for (int kb = 0; kb < 512; kb += 64) {
    {  // stage A: 1 float4/thread (16 lanes x 16B = 256B rows, coalesced)
      const int arow = tid >> 4;
      const int k4   = (tid & 15) * 4;
      *(float4*)(As + arow * 64 + k4) =
          *(const float4*)(A + (size_t)(rbase + arow) * 512 + kb + k4);
      // stage W: 8 float4/thread (32 lanes x 16B = 512B rows, coalesced)
      const int hq4 = (tid & 31) * 4;
      const int w0  = tid >> 5;
#pragma unroll
      for (int p = 0; p < 8; ++p)
        *(float4*)(Ws + (w0 + 8 * p) * 128 + hq4) =
            *(const float4*)(W + (size_t)(kb + w0 + 8 * p) * 128 + hq4);
    }
    __syncthreads();
#pragma unroll 4
    for (int k4 = 0; k4 < 64; k4 += 4) {
      float a[2][4], w[4][4];
      *(float4*)a[0] = *(const float4*)(As + (2 * rg + 0) * 64 + k4);
      *(float4*)a[1] = *(const float4*)(As + (2 * rg + 1) * 64 + k4);
#pragma unroll
      for (int kk = 0; kk < 4; ++kk)
        *(float4*)w[kk] = *(const float4*)(Ws + (k4 + kk) * 128 + 4 * hq);
#pragma unroll
      for (int kk = 0; kk < 4; ++kk)
#pragma unroll
        for (int r = 0; r < 2; ++r)
#pragma unroll
          for (int c = 0; c < 4; ++c)
            acc[r][c] = fmaf(a[r][kk], w[kk][c], acc[r][c]);
    }
    __syncthreads();
  }

#pragma unroll
  for (int r = 0; r < 2; ++r) {
    unsigned int pk[4];
#pragma unroll
    for (int c = 0; c < 4; ++c) {
      const float z  = acc[r][c] * SCALE_IN;
      const float kf = rintf(z);
      const int   ki = (int)kf;
      const float em = __builtin_amdgcn_exp2f(z - kf);   // [0.707,1.414]
      pk[c] = ((unsigned int)ki << 16) |
              (unsigned int)__half_as_ushort(__float2half_rn(em));
    }
    *(uint4*)(O + (size_t)(rbase + 2 * rg + r) * 128 + 4 * hq) = *(uint4*)pk;
  }
}

// ---------------- Main score kernel -----------------------------------------
// Grid 1024 (4 blocks/CU), 256 threads. Tile 64(t) x 32(s); thread 4t x 2s.
// LDS h-chunked (64 h at a time): x1l 16KB + x2l 8KB = 24KB.
__global__ __launch_bounds__(256) void score_kernel(
    const unsigned int* __restrict__ x1w, const unsigned int* __restrict__ x2w,
    const float* __restrict__ v, float* __restrict__ out) {
  __shared__ unsigned int x1l[64 * 64];   // [h_local][t]
  __shared__ unsigned int x2l[64 * 32];   // [h_local][s]

  const int tid   = threadIdx.x;
  const int b     = blockIdx.x >> 7;
  const int tile  = blockIdx.x & 127;
  const int tbase = (tile >> 4) * 64;     // 8 t-tiles
  const int sbase = (tile & 15) * 32;     // 16 s-tiles

  const int sg = tid & 15;    // s = 2*sg + {0,1}
  const int tg = tid >> 4;    // t = 4*tg + {0..3}

  const int st_t = tid >> 2, st_q = tid & 3;   // x1 staging: t 0..63
  const int s2_t = tid >> 3, s2_q = tid & 7;   // x2 staging: s 0..31

  const uint4* x1g = (const uint4*)x1w + (size_t)(b * 512 + tbase) * 32;
  const uint4* x2g = (const uint4*)x2w + (size_t)(b * 512 + sbase) * 32;

  vf2 racc[4];
#pragma unroll
  for (int i = 0; i < 4; ++i) racc[i] = (vf2){0.0f, 0.0f};
  float sv = 0.0f;

  for (int c = 0; c < 2; ++c) {
    if (c) __syncthreads();   // protect previous chunk's reads
    // stage x1: lanes 0..3 share t, consecutive hq -> 64B-coalesced global;
    // LDS write bank = t%32, 4-way (cheap, few instrs)
#pragma unroll
    for (int p = 0; p < 4; ++p) {
      const int hq = st_q + 4 * p;
      const uint4 a = x1g[(size_t)st_t * 32 + 16 * c + hq];
      x1l[(4 * hq + 0) * 64 + st_t] = a.x;
      x1l[(4 * hq + 1) * 64 + st_t] = a.y;
      x1l[(4 * hq + 2) * 64 + st_t] = a.z;
      x1l[(4 * hq + 3) * 64 + st_t] = a.w;
    }
#pragma unroll
    for (int p = 0; p < 2; ++p) {
      const int hq = s2_q + 8 * p;
      const uint4 a = x2g[(size_t)s2_t * 32 + 16 * c + hq];
      x2l[(4 * hq + 0) * 32 + s2_t] = a.x;
      x2l[(4 * hq + 1) * 32 + s2_t] = a.y;
      x2l[(4 * hq + 2) * 32 + s2_t] = a.z;
      x2l[(4 * hq + 3) * 32 + s2_t] = a.w;
    }
    __syncthreads();

    for (int hg = 0; hg < 16; ++hg) {
      const int h0 = 4 * hg;
      const float4 vq = *(const float4*)(v + 64 * c + h0);   // uniform
      sv += (vq.x + vq.y) + (vq.z + vq.w);

      float emt[4][4]; int kt[4][4];
      vf2 ems[4]; int ks[4][2];
#pragma unroll
      for (int qq = 0; qq < 4; ++qq) {
        const uint4 tp = *(const uint4*)(x1l + (h0 + qq) * 64 + 4 * tg);
        emt[qq][0] = __half2float(__ushort_as_half((unsigned short)tp.x));
        kt [qq][0] = ((int)tp.x) >> 16;
        emt[qq][1] = __half2float(__ushort_as_half((unsigned short)tp.y));
        kt [qq][1] = ((int)tp.y) >> 16;
        emt[qq][2] = __half2float(__ushort_as_half((unsigned short)tp.z));
        kt [qq][2] = ((int)tp.z) >> 16;
        emt[qq][3] = __half2float(__ushort_as_half((unsigned short)tp.w));
        kt [qq][3] = ((int)tp.w) >> 16;
        const uint2 sp = *(const uint2*)(x2l + (h0 + qq) * 32 + 2 * sg);
        ems[qq].x = __half2float(__ushort_as_half((unsigned short)sp.x));
        ems[qq].y = __half2float(__ushort_as_half((unsigned short)sp.y));
        ks [qq][0] = ((int)sp.x) >> 16;
        ks [qq][1] = ((int)sp.y) >> 16;
      }

#pragma unroll
      for (int i = 0; i < 4; ++i) {
        vf2 Aq[4];
#pragma unroll
        for (int qq = 0; qq < 4; ++qq) {
          const int k0 = min(kt[qq][i] + ks[qq][0], 30);  // den <= 2^125
          const int k1 = min(kt[qq][i] + ks[qq][1], 30);
          const vf2 m = emt[qq][i] * ems[qq];             // v_pk_mul_f32
          vf2 e; e.x = ldexpf(m.x, k0); e.y = ldexpf(m.y, k1);
          Aq[qq] = e + 1.0f;                              // v_pk_add_f32
        }
        // 4-way-over-h rcp merge, lane-parallel in both s-halves
        const vf2 N01 = vq.x * Aq[1] + vq.y * Aq[0];
        const vf2 N23 = vq.z * Aq[3] + vq.w * Aq[2];
        const vf2 D01 = Aq[0] * Aq[1];
        const vf2 D23 = Aq[2] * Aq[3];
        const vf2 NUM = N01 * D23 + N23 * D01;
        const vf2 DEN = D01 * D23;
        vf2 R;
        R.x = __builtin_amdgcn_rcpf(DEN.x);
        R.y = __builtin_amdgcn_rcpf(DEN.y);
        racc[i] += NUM * R;
      }
    }
  }

  const float c1 = sv * INV_SCALE;
  const float c2 = -2.0f * INV_SCALE;
#pragma unroll
  for (int i = 0; i < 4; ++i) {
    const vf2 o = c2 * racc[i] + c1;
    *(vf2*)(out + (size_t)(b * 512 + tbase + 4 * tg + i) * 512 + sbase + 2 * sg) = o;
  }
}

extern "C" void kernel_launch(void* const* d_in, const int* in_sizes, int n_in,
                              void* d_out, int out_size, void* d_ws, size_t ws_size,
                              hipStream_t stream) {
  const float* query = (const float*)d_in[0];  // (8,512,512)
  const float* keys  = (const float*)d_in[1];  // (8,512,512)
  const float* W1    = (const float*)d_in[2];  // (512,128) pairs with keys
  const float* W2    = (const float*)d_in[3];  // (512,128) pairs with query
  const float* v     = (const float*)d_in[4];  // (128,)
  float* out = (float*)d_out;                  // (8,512,512) fp32

  unsigned int* x1w = (unsigned int*)d_ws;     // 2 MB
  unsigned int* x2w = x1w + 8 * 512 * 128;     // 2 MB

  hipLaunchKernelGGL(proj_kernel, dim3(512), dim3(256), 0, stream,
                     query, W2, keys, W1, x1w, x2w);
  hipLaunchKernelGGL(score_kernel, dim3(1024), dim3(256), 0, stream,
                     x1w, x2w, v, out);
}